// Round 7
// baseline (646.214 us; speedup 1.0000x reference)
//
#include <hip/hip_runtime.h>

#define NN 100000
#define NE 1600000
#define DF 32
#define KIT 5
#define MU 0.01f
#define NSLOT 256
#define NV4 (NN * DF / 4)

#define SCAN_CHUNK 1024
#define SCAN_NB ((NN + SCAN_CHUNK - 1) / SCAN_CHUNK)  // 98 blocks

// ---------- one-time CSR build (row is iteration-invariant) ----------

__global__ __launch_bounds__(256) void zero_deg_kernel(int* __restrict__ deg) {
    int i = blockIdx.x * blockDim.x + threadIdx.x;
    if (i < NN) deg[i] = 0;
}

__global__ __launch_bounds__(256) void hist_kernel(const int* __restrict__ row,
                                                   int* __restrict__ deg) {
    int e = blockIdx.x * blockDim.x + threadIdx.x;
    if (e < NE) atomicAdd(&deg[row[e]], 1);
}

__global__ __launch_bounds__(256) void blocksum_kernel(const int* __restrict__ deg,
                                                       int* __restrict__ bsum) {
    const int t = threadIdx.x;
    const int base = blockIdx.x * SCAN_CHUNK + t * 4;
    int s = 0;
    #pragma unroll
    for (int i = 0; i < 4; ++i) {
        int idx = base + i;
        if (idx < NN) s += deg[idx];
    }
    #pragma unroll
    for (int m = 32; m > 0; m >>= 1) s += __shfl_xor(s, m, 64);
    __shared__ int sm[4];
    if ((t & 63) == 0) sm[t >> 6] = s;
    __syncthreads();
    if (t == 0) bsum[blockIdx.x] = sm[0] + sm[1] + sm[2] + sm[3];
}

__global__ __launch_bounds__(128) void scanbsum_kernel(int* __restrict__ bsum) {
    __shared__ int sh[SCAN_NB];
    const int t = threadIdx.x;
    if (t < SCAN_NB) sh[t] = bsum[t];
    __syncthreads();
    if (t == 0) {
        int run = 0;
        for (int i = 0; i < SCAN_NB; ++i) {
            int v = sh[i];
            sh[i] = run;
            run += v;
        }
    }
    __syncthreads();
    if (t < SCAN_NB) bsum[t] = sh[t];
}

__global__ __launch_bounds__(256) void scanfinal_kernel(const int* __restrict__ deg,
                                                        const int* __restrict__ bsum,
                                                        int* __restrict__ rowptr,
                                                        int* __restrict__ cursor) {
    const int t = threadIdx.x;
    const int base = blockIdx.x * SCAN_CHUNK + t * 4;
    int d[4];
    int s = 0;
    #pragma unroll
    for (int i = 0; i < 4; ++i) {
        int idx = base + i;
        d[i] = (idx < NN) ? deg[idx] : 0;
        s += d[i];
    }
    __shared__ int sh[256];
    sh[t] = s;
    __syncthreads();
    for (int off = 1; off < 256; off <<= 1) {
        int v = (t >= off) ? sh[t - off] : 0;
        __syncthreads();
        sh[t] += v;
        __syncthreads();
    }
    int run = bsum[blockIdx.x] + sh[t] - s;
    #pragma unroll
    for (int i = 0; i < 4; ++i) {
        int idx = base + i;
        if (idx < NN) {
            rowptr[idx] = run;
            cursor[idx] = run;
            run += d[i];
        }
    }
    if (blockIdx.x == 0 && t == 0) rowptr[NN] = NE;
}

__global__ __launch_bounds__(256) void fill_kernel(const int* __restrict__ row,
                                                   const int* __restrict__ col,
                                                   int* __restrict__ cursor,
                                                   int* __restrict__ colsorted) {
    int e = blockIdx.x * blockDim.x + threadIdx.x;
    if (e < NE) {
        int pos = atomicAdd(&cursor[row[e]], 1);
        colsorted[pos] = col[e];
    }
}

// ---------- bf16 shadow helpers ----------

__device__ __forceinline__ unsigned int pack2bf(float a, float b) {
    unsigned int ua = __float_as_uint(a);
    unsigned int ub = __float_as_uint(b);
    return ((ua + 0x8000u) >> 16) | (((ub + 0x8000u) >> 16) << 16);
}

// h_in (fp32) -> hb (bf16 shadow), once at launch start
__global__ __launch_bounds__(256) void tobf16_kernel(const float4* __restrict__ h,
                                                     uint2* __restrict__ hb) {
    int i = blockIdx.x * blockDim.x + threadIdx.x;
    if (i < NV4) {
        const float4 v = h[i];
        hb[i] = make_uint2(pack2bf(v.x, v.y), pack2bf(v.z, v.w));
    }
}

// ---------- per-iteration ----------

// One 32-lane group per node. lane = oct(2b)*8 + fl(3b). Gathers from the
// bf16 shadow: each lane loads uint2 (4 bf16 feats), an octet covers one 64B
// row, the group fetches 4 rows/load. 16 edges in flight (4 independent
// shuffle chains). Tail edges gather the node's own row -> d==0 exactly.
__global__ __launch_bounds__(256) void agg_kernel(const uint2* __restrict__ hb,
                                                  const int* __restrict__ rowptr,
                                                  const int* __restrict__ colsorted,
                                                  float* __restrict__ S,
                                                  int* __restrict__ maxslots) {
    const int lane = threadIdx.x & 31;
    const int oct = lane >> 3;
    const int fl = lane & 7;
    const int node = (blockIdx.x * blockDim.x + threadIdx.x) >> 5;

    const uint2 hru = hb[node * 8 + fl];
    const float hrx = __uint_as_float(hru.x << 16);
    const float hry = __uint_as_float(hru.x & 0xffff0000u);
    const float hrz = __uint_as_float(hru.y << 16);
    const float hrw = __uint_as_float(hru.y & 0xffff0000u);

    const int start = rowptr[node];
    const int end = rowptr[node + 1];

    float4 acc = make_float4(0.f, 0.f, 0.f, 0.f);
    float nmax = 0.0f;

    for (int k = start; k < end; k += 16) {
        int c[4];
        #pragma unroll
        for (int j = 0; j < 4; ++j) {
            const int e = k + 4 * j + oct;
            c[j] = (e < end) ? colsorted[e] : node;
        }
        uint2 u[4];
        #pragma unroll
        for (int j = 0; j < 4; ++j) u[j] = hb[c[j] * 8 + fl];

        float dx[4], dy[4], dz[4], dw[4], s[4];
        #pragma unroll
        for (int j = 0; j < 4; ++j) {
            dx[j] = hrx - __uint_as_float(u[j].x << 16);
            dy[j] = hry - __uint_as_float(u[j].x & 0xffff0000u);
            dz[j] = hrz - __uint_as_float(u[j].y << 16);
            dw[j] = hrw - __uint_as_float(u[j].y & 0xffff0000u);
            s[j] = dx[j] * dx[j] + dy[j] * dy[j] + dz[j] * dz[j] + dw[j] * dw[j];
        }
        #pragma unroll
        for (int m = 1; m < 8; m <<= 1) {
            s[0] += __shfl_xor(s[0], m, 32);
            s[1] += __shfl_xor(s[1], m, 32);
            s[2] += __shfl_xor(s[2], m, 32);
            s[3] += __shfl_xor(s[3], m, 32);
        }
        #pragma unroll
        for (int j = 0; j < 4; ++j) {
            const float n = fmaxf(sqrtf(s[j]), 1e-6f);
            nmax = fmaxf(nmax, n);
            const float w = rsqrtf(n);
            acc.x -= dx[j] * w;
            acc.y -= dy[j] * w;
            acc.z -= dz[j] * w;
            acc.w -= dw[j] * w;
        }
    }

    // cross-octet reduce of acc (features align across octets)
    #pragma unroll
    for (int m = 8; m < 32; m <<= 1) {
        acc.x += __shfl_xor(acc.x, m, 32);
        acc.y += __shfl_xor(acc.y, m, 32);
        acc.z += __shfl_xor(acc.z, m, 32);
        acc.w += __shfl_xor(acc.w, m, 32);
    }
    if (oct == 0) ((float4*)S)[node * 8 + fl] = acc;

    // group max -> wave max -> spread atomic
    nmax = fmaxf(nmax, __shfl_xor(nmax, 8, 32));
    nmax = fmaxf(nmax, __shfl_xor(nmax, 16, 32));
    nmax = fmaxf(nmax, __shfl_xor(nmax, 32, 64));
    if ((threadIdx.x & 63) == 0) {
        // positive floats order like ints; 0xAA poison is negative -> loses
        atomicMax(&maxslots[blockIdx.x & (NSLOT - 1)], __float_as_int(nmax));
    }
}

// h_out = h_in - MU*sqrt(M)*S (fp32), plus refresh of the bf16 shadow.
__global__ __launch_bounds__(256) void update_kernel(const float4* __restrict__ hcur,
                                                     float4* __restrict__ hnxt,
                                                     uint2* __restrict__ hb,
                                                     const float4* __restrict__ S,
                                                     const int* __restrict__ slots) {
    const int t = threadIdx.x;
    int v = slots[t];
    #pragma unroll
    for (int m = 32; m > 0; m >>= 1) v = max(v, __shfl_xor(v, m, 64));
    __shared__ int sm[4];
    __shared__ float sscale;
    if ((t & 63) == 0) sm[t >> 6] = v;
    __syncthreads();
    if (t == 0) {
        int bm = max(max(sm[0], sm[1]), max(sm[2], sm[3]));
        sscale = MU * sqrtf(__int_as_float(bm));
    }
    __syncthreads();
    const float scale = sscale;
    const int i = blockIdx.x * blockDim.x + t;
    if (i < NV4) {
        const float4 hv = hcur[i];
        const float4 sv = S[i];
        float4 o;
        o.x = hv.x - scale * sv.x;
        o.y = hv.y - scale * sv.y;
        o.z = hv.z - scale * sv.z;
        o.w = hv.w - scale * sv.w;
        hnxt[i] = o;
        hb[i] = make_uint2(pack2bf(o.x, o.y), pack2bf(o.z, o.w));
    }
}

extern "C" void kernel_launch(void* const* d_in, const int* in_sizes, int n_in,
                              void* d_out, int out_size, void* d_ws, size_t ws_size,
                              hipStream_t stream) {
    const float* h_in = (const float*)d_in[0];
    const int* row = (const int*)d_in[1];
    const int* col = row + NE;
    float* out = (float*)d_out;

    float* S = (float*)d_ws;                        // NN*DF f32
    int* maxslots = (int*)(S + NN * DF);            // KIT*NSLOT
    int* deg = maxslots + KIT * NSLOT;              // NN
    int* rowptr = deg + NN;                         // NN+1
    int* cursor = rowptr + NN + 1;                  // NN
    int* bsum = cursor + NN;                        // SCAN_NB
    int* colsorted = bsum + SCAN_NB;                // NE
    // bf16 shadow, 16B-aligned
    uintptr_t p = (uintptr_t)(colsorted + NE);
    p = (p + 15) & ~(uintptr_t)15;
    uint2* hb = (uint2*)p;                          // NN*DF bf16 = 6.4 MB

    const int eb = (NE + 255) / 256;
    const int nb = (NN + 255) / 256;
    const int gb = (NN * 32 + 255) / 256;           // 12500
    const int ub = (NV4 + 255) / 256;               // 3125

    zero_deg_kernel<<<nb, 256, 0, stream>>>(deg);
    hist_kernel<<<eb, 256, 0, stream>>>(row, deg);
    blocksum_kernel<<<SCAN_NB, 256, 0, stream>>>(deg, bsum);
    scanbsum_kernel<<<1, 128, 0, stream>>>(bsum);
    scanfinal_kernel<<<SCAN_NB, 256, 0, stream>>>(deg, bsum, rowptr, cursor);
    fill_kernel<<<eb, 256, 0, stream>>>(row, col, cursor, colsorted);
    tobf16_kernel<<<ub, 256, 0, stream>>>((const float4*)h_in, hb);

    for (int it = 0; it < KIT; ++it) {
        const float* cur = (it == 0) ? h_in : out;
        agg_kernel<<<gb, 256, 0, stream>>>(hb, rowptr, colsorted, S,
                                           maxslots + it * NSLOT);
        update_kernel<<<ub, 256, 0, stream>>>((const float4*)cur, (float4*)out, hb,
                                              (const float4*)S,
                                              maxslots + it * NSLOT);
    }
}

// Round 8
// 632.955 us; speedup vs baseline: 1.0209x; 1.0209x over previous
//
#include <hip/hip_runtime.h>

#define NN 100000
#define NE 1600000
#define DF 32
#define KIT 5
#define MU 0.01f
#define NSLOT 256
#define NV4 (NN * DF / 4)

#define SCAN_CHUNK 1024
#define SCAN_NB ((NN + SCAN_CHUNK - 1) / SCAN_CHUNK)  // 98 blocks

// ---------- one-time CSR build (row is iteration-invariant) ----------

__global__ __launch_bounds__(256) void zero_deg_kernel(int* __restrict__ deg) {
    int i = blockIdx.x * blockDim.x + threadIdx.x;
    if (i < NN) deg[i] = 0;
}

__global__ __launch_bounds__(256) void hist_kernel(const int* __restrict__ row,
                                                   int* __restrict__ deg) {
    int e = blockIdx.x * blockDim.x + threadIdx.x;
    if (e < NE) atomicAdd(&deg[row[e]], 1);
}

__global__ __launch_bounds__(256) void blocksum_kernel(const int* __restrict__ deg,
                                                       int* __restrict__ bsum) {
    const int t = threadIdx.x;
    const int base = blockIdx.x * SCAN_CHUNK + t * 4;
    int s = 0;
    #pragma unroll
    for (int i = 0; i < 4; ++i) {
        int idx = base + i;
        if (idx < NN) s += deg[idx];
    }
    #pragma unroll
    for (int m = 32; m > 0; m >>= 1) s += __shfl_xor(s, m, 64);
    __shared__ int sm[4];
    if ((t & 63) == 0) sm[t >> 6] = s;
    __syncthreads();
    if (t == 0) bsum[blockIdx.x] = sm[0] + sm[1] + sm[2] + sm[3];
}

__global__ __launch_bounds__(128) void scanbsum_kernel(int* __restrict__ bsum) {
    __shared__ int sh[SCAN_NB];
    const int t = threadIdx.x;
    if (t < SCAN_NB) sh[t] = bsum[t];
    __syncthreads();
    if (t == 0) {
        int run = 0;
        for (int i = 0; i < SCAN_NB; ++i) {
            int v = sh[i];
            sh[i] = run;
            run += v;
        }
    }
    __syncthreads();
    if (t < SCAN_NB) bsum[t] = sh[t];
}

__global__ __launch_bounds__(256) void scanfinal_kernel(const int* __restrict__ deg,
                                                        const int* __restrict__ bsum,
                                                        int* __restrict__ rowptr,
                                                        int* __restrict__ cursor) {
    const int t = threadIdx.x;
    const int base = blockIdx.x * SCAN_CHUNK + t * 4;
    int d[4];
    int s = 0;
    #pragma unroll
    for (int i = 0; i < 4; ++i) {
        int idx = base + i;
        d[i] = (idx < NN) ? deg[idx] : 0;
        s += d[i];
    }
    __shared__ int sh[256];
    sh[t] = s;
    __syncthreads();
    for (int off = 1; off < 256; off <<= 1) {
        int v = (t >= off) ? sh[t - off] : 0;
        __syncthreads();
        sh[t] += v;
        __syncthreads();
    }
    int run = bsum[blockIdx.x] + sh[t] - s;
    #pragma unroll
    for (int i = 0; i < 4; ++i) {
        int idx = base + i;
        if (idx < NN) {
            rowptr[idx] = run;
            cursor[idx] = run;
            run += d[i];
        }
    }
    if (blockIdx.x == 0 && t == 0) rowptr[NN] = NE;
}

__global__ __launch_bounds__(256) void fill_kernel(const int* __restrict__ row,
                                                   const int* __restrict__ col,
                                                   int* __restrict__ cursor,
                                                   int* __restrict__ colsorted) {
    int e = blockIdx.x * blockDim.x + threadIdx.x;
    if (e < NE) {
        int pos = atomicAdd(&cursor[row[e]], 1);
        colsorted[pos] = col[e];
    }
}

// ---------- bf16 shadow helpers ----------

__device__ __forceinline__ unsigned int pack2bf(float a, float b) {
    unsigned int ua = __float_as_uint(a);
    unsigned int ub = __float_as_uint(b);
    return ((ua + 0x8000u) >> 16) | (((ub + 0x8000u) >> 16) << 16);
}

__device__ __forceinline__ void unpack8(uint4 v, float* f) {
    f[0] = __uint_as_float(v.x << 16);
    f[1] = __uint_as_float(v.x & 0xffff0000u);
    f[2] = __uint_as_float(v.y << 16);
    f[3] = __uint_as_float(v.y & 0xffff0000u);
    f[4] = __uint_as_float(v.z << 16);
    f[5] = __uint_as_float(v.z & 0xffff0000u);
    f[6] = __uint_as_float(v.w << 16);
    f[7] = __uint_as_float(v.w & 0xffff0000u);
}

__global__ __launch_bounds__(256) void tobf16_kernel(const float4* __restrict__ h,
                                                     uint2* __restrict__ hb) {
    int i = blockIdx.x * blockDim.x + threadIdx.x;
    if (i < NV4) {
        const float4 v = h[i];
        hb[i] = make_uint2(pack2bf(v.x, v.y), pack2bf(v.z, v.w));
    }
}

// ---------- per-iteration ----------

// One 32-lane group per node. lane = q(quad id, 3b) * 4 + f2(2b).
// Each lane loads uint4 = 16B = 8 bf16 feats; 4 lanes (a quad) cover one 64B
// row -> 16 rows per wave gather instruction. First 32 edges handled in one
// batch: one coalesced lane-indexed col load + shuffles (no colsorted->gather
// serial dependency), 4 gather instructions issued back-to-back. Tail slots
// gather the node's own row (L1-hot, d==0 exactly). deg>32 falls to an
// 8-edge loop (P(deg>32) ~ 1e-4 at Poisson(16)).
__global__ __launch_bounds__(256) void agg_kernel(const uint4* __restrict__ hb4,
                                                  const int* __restrict__ rowptr,
                                                  const int* __restrict__ colsorted,
                                                  float* __restrict__ S,
                                                  int* __restrict__ maxslots) {
    const int lane = threadIdx.x & 31;
    const int q = lane >> 2;   // row slot within batch (0..7)
    const int f2 = lane & 3;   // 16B chunk within row
    const int node = (blockIdx.x * blockDim.x + threadIdx.x) >> 5;

    const int start = rowptr[node];
    const int end = rowptr[node + 1];

    // issue the two independent "head" loads immediately
    const int eidx = start + lane;
    const int c_all = (eidx < end) ? colsorted[eidx] : node;
    const uint4 hru = hb4[node * 4 + f2];

    float hrf[8];
    unpack8(hru, hrf);

    float acc[8];
    #pragma unroll
    for (int i = 0; i < 8; ++i) acc[i] = 0.0f;
    float nmax = 0.0f;

    // ---- fast batch: first min(deg,32) edges, 4 gathers in flight ----
    uint4 u[4];
    #pragma unroll
    for (int j = 0; j < 4; ++j) {
        const int cj = __shfl(c_all, 8 * j + q, 32);
        u[j] = hb4[cj * 4 + f2];
    }
    #pragma unroll
    for (int j = 0; j < 4; ++j) {
        float d[8];
        unpack8(u[j], d);
        float s = 0.0f;
        #pragma unroll
        for (int i = 0; i < 8; ++i) {
            d[i] = hrf[i] - d[i];
            s = fmaf(d[i], d[i], s);
        }
        s += __shfl_xor(s, 1, 32);
        s += __shfl_xor(s, 2, 32);
        const float n = fmaxf(sqrtf(s), 1e-6f);
        nmax = fmaxf(nmax, n);
        const float w = rsqrtf(n);
        #pragma unroll
        for (int i = 0; i < 8; ++i) acc[i] = fmaf(-d[i], w, acc[i]);
    }

    // ---- rare tail: deg > 32, 8 edges per step ----
    for (int k = start + 32; k < end; k += 8) {
        const int ei = k + q;
        const int c = (ei < end) ? colsorted[ei] : node;
        const uint4 uu = hb4[c * 4 + f2];
        float d[8];
        unpack8(uu, d);
        float s = 0.0f;
        #pragma unroll
        for (int i = 0; i < 8; ++i) {
            d[i] = hrf[i] - d[i];
            s = fmaf(d[i], d[i], s);
        }
        s += __shfl_xor(s, 1, 32);
        s += __shfl_xor(s, 2, 32);
        const float n = fmaxf(sqrtf(s), 1e-6f);
        nmax = fmaxf(nmax, n);
        const float w = rsqrtf(n);
        #pragma unroll
        for (int i = 0; i < 8; ++i) acc[i] = fmaf(-d[i], w, acc[i]);
    }

    // cross-quad reduce of acc (quads hold different edges, same feats)
    #pragma unroll
    for (int m = 4; m < 32; m <<= 1) {
        #pragma unroll
        for (int i = 0; i < 8; ++i) acc[i] += __shfl_xor(acc[i], m, 32);
    }
    if (q == 0) {
        float4 o0 = make_float4(acc[0], acc[1], acc[2], acc[3]);
        float4 o1 = make_float4(acc[4], acc[5], acc[6], acc[7]);
        ((float4*)S)[node * 8 + f2 * 2] = o0;
        ((float4*)S)[node * 8 + f2 * 2 + 1] = o1;
    }

    // group max -> wave max -> spread atomic
    nmax = fmaxf(nmax, __shfl_xor(nmax, 4, 32));
    nmax = fmaxf(nmax, __shfl_xor(nmax, 8, 32));
    nmax = fmaxf(nmax, __shfl_xor(nmax, 16, 32));
    nmax = fmaxf(nmax, __shfl_xor(nmax, 32, 64));
    if ((threadIdx.x & 63) == 0) {
        // positive floats order like ints; 0xAA poison is negative -> loses
        atomicMax(&maxslots[blockIdx.x & (NSLOT - 1)], __float_as_int(nmax));
    }
}

// h_out = h_in - MU*sqrt(M)*S (fp32), plus refresh of the bf16 shadow.
__global__ __launch_bounds__(256) void update_kernel(const float4* __restrict__ hcur,
                                                     float4* __restrict__ hnxt,
                                                     uint2* __restrict__ hb,
                                                     const float4* __restrict__ S,
                                                     const int* __restrict__ slots) {
    const int t = threadIdx.x;
    int v = slots[t];
    #pragma unroll
    for (int m = 32; m > 0; m >>= 1) v = max(v, __shfl_xor(v, m, 64));
    __shared__ int sm[4];
    __shared__ float sscale;
    if ((t & 63) == 0) sm[t >> 6] = v;
    __syncthreads();
    if (t == 0) {
        int bm = max(max(sm[0], sm[1]), max(sm[2], sm[3]));
        sscale = MU * sqrtf(__int_as_float(bm));
    }
    __syncthreads();
    const float scale = sscale;
    const int i = blockIdx.x * blockDim.x + t;
    if (i < NV4) {
        const float4 hv = hcur[i];
        const float4 sv = S[i];
        float4 o;
        o.x = hv.x - scale * sv.x;
        o.y = hv.y - scale * sv.y;
        o.z = hv.z - scale * sv.z;
        o.w = hv.w - scale * sv.w;
        hnxt[i] = o;
        hb[i] = make_uint2(pack2bf(o.x, o.y), pack2bf(o.z, o.w));
    }
}

extern "C" void kernel_launch(void* const* d_in, const int* in_sizes, int n_in,
                              void* d_out, int out_size, void* d_ws, size_t ws_size,
                              hipStream_t stream) {
    const float* h_in = (const float*)d_in[0];
    const int* row = (const int*)d_in[1];
    const int* col = row + NE;
    float* out = (float*)d_out;

    float* S = (float*)d_ws;                        // NN*DF f32
    int* maxslots = (int*)(S + NN * DF);            // KIT*NSLOT
    int* deg = maxslots + KIT * NSLOT;              // NN
    int* rowptr = deg + NN;                         // NN+1
    int* cursor = rowptr + NN + 1;                  // NN
    int* bsum = cursor + NN;                        // SCAN_NB
    int* colsorted = bsum + SCAN_NB;                // NE
    // bf16 shadow, 16B-aligned
    uintptr_t p = (uintptr_t)(colsorted + NE);
    p = (p + 15) & ~(uintptr_t)15;
    uint2* hb = (uint2*)p;                          // NN*DF bf16 = 6.4 MB

    const int eb = (NE + 255) / 256;
    const int nb = (NN + 255) / 256;
    const int gb = (NN * 32 + 255) / 256;           // 12500
    const int ub = (NV4 + 255) / 256;               // 3125

    zero_deg_kernel<<<nb, 256, 0, stream>>>(deg);
    hist_kernel<<<eb, 256, 0, stream>>>(row, deg);
    blocksum_kernel<<<SCAN_NB, 256, 0, stream>>>(deg, bsum);
    scanbsum_kernel<<<1, 128, 0, stream>>>(bsum);
    scanfinal_kernel<<<SCAN_NB, 256, 0, stream>>>(deg, bsum, rowptr, cursor);
    fill_kernel<<<eb, 256, 0, stream>>>(row, col, cursor, colsorted);
    tobf16_kernel<<<ub, 256, 0, stream>>>((const float4*)h_in, hb);

    for (int it = 0; it < KIT; ++it) {
        const float* cur = (it == 0) ? h_in : out;
        agg_kernel<<<gb, 256, 0, stream>>>((const uint4*)hb, rowptr, colsorted, S,
                                           maxslots + it * NSLOT);
        update_kernel<<<ub, 256, 0, stream>>>((const float4*)cur, (float4*)out, hb,
                                              (const float4*)S,
                                              maxslots + it * NSLOT);
    }
}